// Round 2
// baseline (5304.117 us; speedup 1.0000x reference)
//
#include <hip/hip_runtime.h>
#include <stdint.h>
#include <stddef.h>

#define BATCH 128
#define NFRAMES 256
#define EMBED 768
#define RES 2048
#define NCLS 1000
#define NWG 128

typedef __attribute__((ext_vector_type(8))) short bf16x8;
typedef __attribute__((ext_vector_type(4))) float f32x4;
typedef unsigned short u16;

__device__ inline u16 f2bf(float f) {
    union { float f; unsigned u; } v; v.f = f;
    unsigned r = v.u + 0x7FFFu + ((v.u >> 16) & 1u);
    return (u16)(r >> 16);
}
__device__ inline float bf2f(u16 h) {
    union { unsigned u; float f; } v; v.u = ((unsigned)h) << 16;
    return v.f;
}

// ---------------- fp32 -> bf16 convert, vectorized x4 ----------------
__global__ __launch_bounds__(256) void cvt_kernel(const float* __restrict__ in,
                                                  u16* __restrict__ out, int n4) {
    int i = blockIdx.x * blockDim.x + threadIdx.x;
    int stride = gridDim.x * blockDim.x;
    for (; i < n4; i += stride) {
        float4 v = ((const float4*)in)[i];
        ushort4 o;
        o.x = f2bf(v.x); o.y = f2bf(v.y); o.z = f2bf(v.z); o.w = f2bf(v.w);
        ((ushort4*)out)[i] = o;
    }
}

// ---------------- projection: u[t,b,r] = sum_e x[b,t,e] * W_in[r,e] ----------------
__global__ __launch_bounds__(256) void proj_kernel(const u16* __restrict__ xb,
                                                   const u16* __restrict__ win,
                                                   u16* __restrict__ u) {
    int lane = threadIdx.x & 63;
    int w = threadIdx.x >> 6;
    int wm = w >> 1, wn = w & 1;
    int m0 = blockIdx.x * 128 + wm * 64;
    int n0 = blockIdx.y * 128 + wn * 64;
    int lr = lane & 15;
    int lk = (lane >> 4) * 8;

    f32x4 acc[4][4];
#pragma unroll
    for (int i = 0; i < 4; i++)
#pragma unroll
        for (int j = 0; j < 4; j++) acc[i][j] = (f32x4)0.f;

    for (int kk = 0; kk < EMBED; kk += 32) {
        bf16x8 a[4], b[4];
#pragma unroll
        for (int i = 0; i < 4; i++)
            a[i] = *(const bf16x8*)(xb + (size_t)(m0 + i * 16 + lr) * EMBED + kk + lk);
#pragma unroll
        for (int j = 0; j < 4; j++)
            b[j] = *(const bf16x8*)(win + (size_t)(n0 + j * 16 + lr) * EMBED + kk + lk);
#pragma unroll
        for (int i = 0; i < 4; i++)
#pragma unroll
            for (int j = 0; j < 4; j++)
                acc[i][j] = __builtin_amdgcn_mfma_f32_16x16x32_bf16(a[i], b[j], acc[i][j], 0, 0, 0);
    }

    int rowbase = (lane >> 4) * 4;
#pragma unroll
    for (int i = 0; i < 4; i++) {
#pragma unroll
        for (int j = 0; j < 4; j++) {
#pragma unroll
            for (int q = 0; q < 4; q++) {
                int m = m0 + i * 16 + rowbase + q;   // row index = b*NFRAMES + t
                int n = n0 + j * 16 + lr;            // reservoir index
                int bb = m >> 8, tt = m & 255;
                u[((size_t)tt * BATCH + bb) * RES + n] = f2bf(acc[i][j][q]);
            }
        }
    }
}

// ---------------- grid barrier (device-scope, sense via generation counter) ----------------
__device__ inline void grid_barrier(unsigned* cnt, unsigned* gen) {
    __syncthreads();
    if (threadIdx.x == 0) {
        __builtin_amdgcn_fence(__ATOMIC_RELEASE, "agent");  // write back this XCD's L2
        unsigned g = __hip_atomic_load(gen, __ATOMIC_RELAXED, __HIP_MEMORY_SCOPE_AGENT);
        unsigned a = __hip_atomic_fetch_add(cnt, 1u, __ATOMIC_RELAXED, __HIP_MEMORY_SCOPE_AGENT);
        if (a == NWG - 1) {
            __hip_atomic_store(cnt, 0u, __ATOMIC_RELAXED, __HIP_MEMORY_SCOPE_AGENT);
            __hip_atomic_store(gen, g + 1u, __ATOMIC_RELEASE, __HIP_MEMORY_SCOPE_AGENT);
        } else {
            while (__hip_atomic_load(gen, __ATOMIC_RELAXED, __HIP_MEMORY_SCOPE_AGENT) == g)
                __builtin_amdgcn_s_sleep(1);
        }
        __builtin_amdgcn_fence(__ATOMIC_ACQUIRE, "agent");  // invalidate L1/L2 (stale state lines)
    }
    __syncthreads();
}

// ---------------- persistent recurrence: all 256 steps in one launch ----------------
// 128 WGs, each owns output tile [64 rows x 32 cols]. 8 waves: M-split 4 x K-split 2.
// new_state[b,r] = tanh( sum_k state[b,k]*res[r,k] + u_t[b,r] )
__global__ __launch_bounds__(512) void recur_kernel(const u16* __restrict__ res,
                                                    const u16* __restrict__ u,
                                                    u16* __restrict__ s0,
                                                    u16* __restrict__ s1,
                                                    unsigned* bar) {
    __shared__ float part[2][64][33];
    const int wg = blockIdx.x;
    const int m0 = (wg >> 6) * 64;   // 0 or 64
    const int n0 = (wg & 63) * 32;   // 0..2016
    const int lane = threadIdx.x & 63;
    const int w = threadIdx.x >> 6;
    const int mq = w & 3;            // M quarter (16 rows)
    const int kh = w >> 2;           // K half (1024)
    const int lr = lane & 15;
    const int lk = (lane >> 4) * 8;
    const int rb = (lane >> 4) * 4;
    const int arow = m0 + mq * 16 + lr;

    const u16* bbase0 = res + (size_t)(n0 + lr) * RES + kh * 1024 + lk;
    const u16* bbase1 = bbase0 + (size_t)16 * RES;

    for (int t = 0; t < NFRAMES; t++) {
        const u16* sin = (t & 1) ? s1 : s0;
        u16* sout = (t & 1) ? s0 : s1;
        const u16* abase = sin + (size_t)arow * RES + kh * 1024 + lk;

        f32x4 acc0 = (f32x4)0.f, acc1 = (f32x4)0.f;
#pragma unroll
        for (int ki = 0; ki < 32; ki++) {
            bf16x8 a  = *(const bf16x8*)(abase + ki * 32);
            bf16x8 b0 = *(const bf16x8*)(bbase0 + ki * 32);
            bf16x8 b1 = *(const bf16x8*)(bbase1 + ki * 32);
            acc0 = __builtin_amdgcn_mfma_f32_16x16x32_bf16(a, b0, acc0, 0, 0, 0);
            acc1 = __builtin_amdgcn_mfma_f32_16x16x32_bf16(a, b1, acc1, 0, 0, 0);
        }
#pragma unroll
        for (int q = 0; q < 4; q++) {
            part[kh][mq * 16 + rb + q][lr]      = acc0[q];
            part[kh][mq * 16 + rb + q][16 + lr] = acc1[q];
        }
        __syncthreads();
#pragma unroll
        for (int k = 0; k < 4; k++) {
            int idx = threadIdx.x + k * 512;
            int r = idx >> 5, c = idx & 31;
            float s = part[0][r][c] + part[1][r][c];
            float val = tanhf(s + bf2f(u[((size_t)t * BATCH + m0 + r) * RES + n0 + c]));
            sout[(size_t)(m0 + r) * RES + n0 + c] = f2bf(val);
        }
        if (t != NFRAMES - 1) grid_barrier(bar, bar + 64);
        // barrier entry __syncthreads also protects `part` reuse next iteration
    }
}

// ---------------- head: logits[b,c] = sum_r s[b,r]*W_out[c,r] + bias[c] ----------------
__global__ __launch_bounds__(512) void head_kernel(const u16* __restrict__ sin,
                                                   const u16* __restrict__ wout,
                                                   const float* __restrict__ bias,
                                                   float* __restrict__ out) {
    __shared__ float part[8][32][33];
    int lane = threadIdx.x & 63;
    int w = threadIdx.x >> 6;
    int m0 = blockIdx.x * 32;
    int n0 = blockIdx.y * 32;   // over padded 1024
    int k0 = w * 256;
    int lr = lane & 15;
    int lk = (lane >> 4) * 8;

    f32x4 acc[2][2];
#pragma unroll
    for (int i = 0; i < 2; i++)
#pragma unroll
        for (int j = 0; j < 2; j++) acc[i][j] = (f32x4)0.f;

    for (int kk = k0; kk < k0 + 256; kk += 32) {
        bf16x8 a[2], b[2];
#pragma unroll
        for (int i = 0; i < 2; i++)
            a[i] = *(const bf16x8*)(sin + (size_t)(m0 + i * 16 + lr) * RES + kk + lk);
#pragma unroll
        for (int j = 0; j < 2; j++) {
            int row = n0 + j * 16 + lr;
            if (row > NCLS - 1) row = NCLS - 1;  // clamp, result unused
            b[j] = *(const bf16x8*)(wout + (size_t)row * RES + kk + lk);
        }
#pragma unroll
        for (int i = 0; i < 2; i++)
#pragma unroll
            for (int j = 0; j < 2; j++)
                acc[i][j] = __builtin_amdgcn_mfma_f32_16x16x32_bf16(a[i], b[j], acc[i][j], 0, 0, 0);
    }

    int rowbase = (lane >> 4) * 4;
#pragma unroll
    for (int i = 0; i < 2; i++)
#pragma unroll
        for (int j = 0; j < 2; j++)
#pragma unroll
            for (int q = 0; q < 4; q++)
                part[w][i * 16 + rowbase + q][j * 16 + lr] = acc[i][j][q];

    __syncthreads();

    for (int idx = threadIdx.x; idx < 1024; idx += 512) {
        int r = idx >> 5, c = idx & 31;
        float s = 0.f;
#pragma unroll
        for (int ww = 0; ww < 8; ww++) s += part[ww][r][c];
        int cg = n0 + c;
        if (cg < NCLS)
            out[(size_t)(m0 + r) * NCLS + cg] = s + bias[cg];
    }
}

extern "C" void kernel_launch(void* const* d_in, const int* in_sizes, int n_in,
                              void* d_out, int out_size, void* d_ws, size_t ws_size,
                              hipStream_t stream) {
    const float* x_f    = (const float*)d_in[0];  // [128,256,768]
    const float* res_f  = (const float*)d_in[1];  // [2048,2048]
    const float* win_f  = (const float*)d_in[2];  // [2048,768]
    const float* wout_f = (const float*)d_in[3];  // [1000,2048]
    const float* bias   = (const float*)d_in[4];  // [1000]
    float* out = (float*)d_out;

    char* ws = (char*)d_ws;
    size_t off = 0;
    auto alloc = [&](size_t bytes) -> void* {
        void* p = ws + off;
        off += (bytes + 255) & ~(size_t)255;
        return p;
    };
    u16* res_b  = (u16*)alloc((size_t)RES * RES * 2);
    u16* win_b  = (u16*)alloc((size_t)RES * EMBED * 2);
    u16* wout_b = (u16*)alloc((size_t)NCLS * RES * 2);
    u16* x_b    = (u16*)alloc((size_t)BATCH * NFRAMES * EMBED * 2);
    u16* u      = (u16*)alloc((size_t)NFRAMES * BATCH * RES * 2);
    u16* s0     = (u16*)alloc((size_t)BATCH * RES * 2);
    u16* s1     = (u16*)alloc((size_t)BATCH * RES * 2);
    unsigned* bar = (unsigned*)alloc(1024);

    // weight / input conversion to bf16
    cvt_kernel<<<dim3(1024), dim3(256), 0, stream>>>(res_f, res_b, RES * RES / 4);
    cvt_kernel<<<dim3(512), dim3(256), 0, stream>>>(win_f, win_b, RES * EMBED / 4);
    cvt_kernel<<<dim3(512), dim3(256), 0, stream>>>(wout_f, wout_b, NCLS * RES / 4);
    cvt_kernel<<<dim3(2048), dim3(256), 0, stream>>>(x_f, x_b, BATCH * NFRAMES * EMBED / 4);

    // state0 = 0, barrier state = 0 (ws is poisoned 0xAA; must re-init every call)
    hipMemsetAsync(s0, 0, (size_t)BATCH * RES * 2, stream);
    hipMemsetAsync(bar, 0, 1024, stream);

    // u[t,b,r] projection GEMM
    proj_kernel<<<dim3(256, 16), dim3(256), 0, stream>>>(x_b, win_b, u);

    // all 256 recurrence steps in one cooperative launch
    void* args[] = { (void*)&res_b, (void*)&u, (void*)&s0, (void*)&s1, (void*)&bar };
    hipLaunchCooperativeKernel((const void*)recur_kernel, dim3(NWG), dim3(512),
                               args, 0, stream);

    // final state is in s0 (t=255 odd -> wrote s0)
    head_kernel<<<dim3(4, 32), dim3(512), 0, stream>>>(s0, wout_b, bias, out);
}